// Round 8
// baseline (285.445 us; speedup 1.0000x reference)
//
#include <hip/hip_runtime.h>
#include <cstddef>
#include <cstdint>

#define Hdim 64
#define Wdim 64
#define NH 4
#define DH 32
#define KW 7
#define QSCALE 0.17677669529663687f

typedef _Float16 v2h __attribute__((ext_vector_type(2)));
typedef _Float16 half8 __attribute__((ext_vector_type(8)));
typedef float f32x4 __attribute__((ext_vector_type(4)));

#if defined(__has_builtin)
#if __has_builtin(__builtin_amdgcn_fdot2)
#define HAVE_FDOT2 1
#endif
#endif

__device__ __forceinline__ float fdot2acc(v2h a, v2h b, float c) {
#ifdef HAVE_FDOT2
    return __builtin_amdgcn_fdot2(a, b, c, false);
#else
    return fmaf((float)a.x, (float)b.x, fmaf((float)a.y, (float)b.y, c));
#endif
}

union F16x8 {
    uint4 u;
    v2h h[4];
};

// ---------------------------------------------------------------------------
// Prep: transpose + fp16-convert weights. WT[n][k], k contiguous (128).
// ---------------------------------------------------------------------------
__global__ __launch_bounds__(256) void prep_weights(
    const float* __restrict__ wq, const float* __restrict__ wp,
    _Float16* __restrict__ wqT, _Float16* __restrict__ wpT)
{
    __shared__ float Ts[64][65];
    int blk = blockIdx.x;
    const float* src;
    _Float16* dst;
    int N, kt, nt;
    if (blk < 12) { src = wq; dst = wqT; N = 384; kt = blk / 6; nt = blk % 6; }
    else { blk -= 12; src = wp; dst = wpT; N = 128; kt = blk >> 1; nt = blk & 1; }
    const int k0 = kt * 64, n0 = nt * 64;
    const int tid = threadIdx.x;

#pragma unroll
    for (int it = 0; it < 16; ++it) {
        int idx = it * 256 + tid;
        int r = idx >> 6, c = idx & 63;
        Ts[r][c] = src[(size_t)(k0 + r) * N + n0 + c];
    }
    __syncthreads();
#pragma unroll
    for (int it = 0; it < 2; ++it) {
        int idx = it * 256 + tid;
        int n = idx >> 3;
        int kq = (idx & 7) * 8;
        _Float16 tmp[8];
#pragma unroll
        for (int j = 0; j < 8; ++j) tmp[j] = (_Float16)Ts[kq + j][n];
        *(uint4*)(dst + (size_t)(n0 + n) * 128 + k0 + kq) = *(const uint4*)tmp;
    }
}

// ---------------------------------------------------------------------------
// GEMM1 (MFMA): qkv = x @ w_qkv + b_qkv -> fp16 [sel][b*4+h][yx][32], q scaled.
// (R4 verbatim — LDS-swizzled coalesced epilogue.)
// ---------------------------------------------------------------------------
__global__ __launch_bounds__(256) void gemm_qkv_mfma(
    const float* __restrict__ A,      // x [16384][128]
    const _Float16* __restrict__ WT,  // [384][128]
    const float* __restrict__ bias,   // [384]
    _Float16* __restrict__ qkvh)      // [3][16][4096][32]
{
    __shared__ _Float16 As[64 * 136];
    const int m0 = blockIdx.x * 64;
    const int sel = blockIdx.y;
    const int n0 = sel * 128;
    const int tid = threadIdx.x;
    const int wv = tid >> 6;
    const int ln = tid & 15;
    const int quad = (tid & 63) >> 4;

#pragma unroll
    for (int it = 0; it < 8; ++it) {
        int idx = it * 256 + tid;
        int m = idx >> 5;
        int kq = (idx & 31) * 4;
        float4 a = *(const float4*)(A + (size_t)(m0 + m) * 128 + kq);
        _Float16 t[4] = {(_Float16)a.x, (_Float16)a.y, (_Float16)a.z, (_Float16)a.w};
        *(uint2*)(As + m * 136 + kq) = *(const uint2*)t;
    }
    __syncthreads();

    f32x4 acc[8] = {};
    const int mrow = wv * 16 + ln;
#pragma unroll
    for (int ks = 0; ks < 4; ++ks) {
        const half8 af = *(const half8*)(As + mrow * 136 + ks * 32 + quad * 8);
#pragma unroll
        for (int nt = 0; nt < 8; ++nt) {
            const half8 bf = *(const half8*)(WT + (size_t)(n0 + nt * 16 + ln) * 128 + ks * 32 + quad * 8);
            acc[nt] = __builtin_amdgcn_mfma_f32_16x16x32_f16(af, bf, acc[nt], 0, 0, 0);
        }
    }
    __syncthreads();

    const float qscale = (sel == 0) ? QSCALE : 1.0f;
#pragma unroll
    for (int nt = 0; nt < 8; ++nt) {
        const int n = nt * 16 + ln;
        const float bv = bias[n0 + n];
#pragma unroll
        for (int r = 0; r < 4; ++r) {
            const int m = wv * 16 + quad * 4 + r;
            As[m * 136 + n] = (_Float16)((acc[nt][r] + bv) * qscale);
        }
    }
    __syncthreads();

    const int b = m0 >> 12;
    const int yx0 = m0 & 4095;
#pragma unroll
    for (int h = 0; h < 4; ++h) {
        const int r = tid >> 2;
        const int c = tid & 3;
        uint4 v = *(const uint4*)(As + r * 136 + h * 32 + c * 8);
        *(uint4*)(qkvh + (((size_t)sel * 16 + b * 4 + h) * 4096 + yx0 + r) * 32 + c * 8) = v;
    }
}

// ---------------------------------------------------------------------------
// Fused attention + output projection, 512 threads (8 waves).
// Thread = (head, pixel, 16-dim half): h=tid>>7, p=(tid>>1)&63, q2=tid&1.
// __launch_bounds__(512,2): 2 waves/EU -> 256 VGPR budget, so even an
// arch/acc split (MFMA in-kernel) leaves 128 arch regs for the ~90-reg
// attention body. R5-R7's 1024-thr variants were pinned at 64 arch VGPRs
// (MFMA split of the 128 budget) -> 400 MB scratch spill.
// LDS ~107 KB -> 1 block/CU; grid 256 = 1/CU, 8 waves/CU.
// ---------------------------------------------------------------------------
#define ATS 8
#define AMAXPOS 196
#define PSTR 136   // halves per position (4 heads x 32 + 8 pad)

__global__ __launch_bounds__(512, 2) void attn_proj(
    const _Float16* __restrict__ qkvh,  // [3][16][4096][32]
    const float* __restrict__ rpb,      // [4][13][13]
    const _Float16* __restrict__ wpT,   // [128][128] (n-major, k contiguous)
    const float* __restrict__ bproj,    // [128]
    float* __restrict__ outp)           // [16384][128]
{
    __shared__ __align__(16) char arena[AMAXPOS * PSTR * 2 * 2 + 169 * NH * 4];
    _Float16* kS = (_Float16*)arena;                       // [196][136]
    _Float16* vS = kS + AMAXPOS * PSTR;                    // [196][136]
    float* rS = (float*)(arena + AMAXPOS * PSTR * 2 * 2);  // [4][169]
    _Float16* Of = kS;                                     // alias: [64][136]
    float* Cs = (float*)vS;                                // alias: [64][132]

    const int b = blockIdx.x;
    const int ty0 = blockIdx.y * ATS;
    const int tx0 = blockIdx.z * ATS;
    const int tid = threadIdx.x;

    const int lo_h = max(0, min(ty0 - 3, Hdim - KW));
    const int hi_h = min(ty0 + ATS - 4, Hdim - KW) + KW - 1;
    const int lo_w = max(0, min(tx0 - 3, Wdim - KW));
    const int hi_w = min(tx0 + ATS - 4, Wdim - KW) + KW - 1;
    const int ch = hi_h - lo_h + 1;
    const int cw = hi_w - lo_w + 1;
    const int npos = ch * cw;

    // ---- stage K/V halo, all 4 heads ----
    for (int idx = tid; idx < npos * 16; idx += 512) {
        const int pos = idx >> 4;
        const int sub = idx & 15;
        const int hh = sub >> 2;
        const int cc = sub & 3;
        const int ry = pos / cw;
        const int rx = pos - ry * cw;
        const size_t g = ((size_t)(lo_h + ry) * Wdim + (lo_w + rx)) * 32 + cc * 8;
        const size_t kpl = ((size_t)(16 + b * 4 + hh)) * 131072;
        const size_t vpl = ((size_t)(32 + b * 4 + hh)) * 131072;
        *(uint4*)(kS + pos * PSTR + hh * 32 + cc * 8) = *(const uint4*)(qkvh + kpl + g);
        *(uint4*)(vS + pos * PSTR + hh * 32 + cc * 8) = *(const uint4*)(qkvh + vpl + g);
    }
    for (int i = tid; i < 169 * NH; i += 512) rS[i] = rpb[i];
    __syncthreads();

    // ---- attention: thread = (head, pixel, 16-dim half) ----
    const int h = tid >> 7;          // head 0..3 (constant within a wave)
    const int p = (tid >> 1) & 63;   // pixel 0..63
    const int q2 = tid & 1;          // 16-dim half (== lane bit 0)
    const int py = p >> 3, px = p & 7;
    const int y = ty0 + py, x = tx0 + px;
    const int sh = max(0, min(y - 3, Hdim - KW));
    const int sw = max(0, min(x - 3, Wdim - KW));
    const int rb = sh - lo_h;
    const int cb = sw - lo_w;
    const int bh0 = sh - y + 6;
    const int bw0 = sw - x + 6;
    const int hq = h * 32 + q2 * 16;

    F16x8 qf0, qf1;
    {
        const _Float16* qp = qkvh + ((size_t)(b * 4 + h)) * 131072 +
                             ((size_t)y * Wdim + x) * 32 + q2 * 16;
        qf0.u = *(const uint4*)(qp);
        qf1.u = *(const uint4*)(qp + 8);
    }

    float sc[49];
#pragma unroll
    for (int i = 0; i < KW; ++i) {
        const _Float16* kp = kS + ((rb + i) * cw + cb) * PSTR + hq;
        const int bi = h * 169 + (bh0 + i) * 13 + bw0;
#pragma unroll
        for (int j = 0; j < KW; ++j) {
            F16x8 kf0, kf1;
            kf0.u = *(const uint4*)(kp + j * PSTR);
            kf1.u = *(const uint4*)(kp + j * PSTR + 8);
            float s = fdot2acc(qf0.h[0], kf0.h[0],
                      fdot2acc(qf0.h[1], kf0.h[1],
                      fdot2acc(qf0.h[2], kf0.h[2],
                      fdot2acc(qf0.h[3], kf0.h[3],
                      fdot2acc(qf1.h[0], kf1.h[0],
                      fdot2acc(qf1.h[1], kf1.h[1],
                      fdot2acc(qf1.h[2], kf1.h[2],
                      fdot2acc(qf1.h[3], kf1.h[3], 0.0f))))))));
            s += __shfl_xor(s, 1);   // sum the two 16-dim halves
            sc[i * KW + j] = s + rS[bi + j];
        }
    }

    float mx = sc[0];
#pragma unroll
    for (int t = 1; t < 49; ++t) mx = fmaxf(mx, sc[t]);
    float l = 0.f;
#pragma unroll
    for (int t = 0; t < 49; ++t) { sc[t] = __expf(sc[t] - mx); l += sc[t]; }
    const float inv = 1.f / l;

    float o[16] = {};
#pragma unroll
    for (int i = 0; i < KW; ++i) {
        const _Float16* vp = vS + ((rb + i) * cw + cb) * PSTR + hq;
#pragma unroll
        for (int j = 0; j < KW; ++j) {
            F16x8 vf0, vf1;
            vf0.u = *(const uint4*)(vp + j * PSTR);
            vf1.u = *(const uint4*)(vp + j * PSTR + 8);
            const float w = sc[i * KW + j] * inv;
#pragma unroll
            for (int d = 0; d < 4; ++d) {
                o[2 * d + 0] = fmaf(w, (float)vf0.h[d].x, o[2 * d + 0]);
                o[2 * d + 1] = fmaf(w, (float)vf0.h[d].y, o[2 * d + 1]);
                o[2 * d + 8] = fmaf(w, (float)vf1.h[d].x, o[2 * d + 8]);
                o[2 * d + 9] = fmaf(w, (float)vf1.h[d].y, o[2 * d + 9]);
            }
        }
    }

    // ---- O -> LDS fp16 (alias over kS) ----
    __syncthreads();
    {
        _Float16 oh[16];
#pragma unroll
        for (int d = 0; d < 16; ++d) oh[d] = (_Float16)o[d];
        *(uint4*)(Of + p * PSTR + hq)     = *(const uint4*)(oh);
        *(uint4*)(Of + p * PSTR + hq + 8) = *(const uint4*)(oh + 8);
    }
    __syncthreads();

    // ---- projection: O(64x128) @ wpT^T + bproj (8 waves) ----
    const int wvid = tid >> 6;        // 0..7
    const int mt = wvid >> 1;         // m-tile 0..3
    const int nhf = wvid & 1;         // n-half 0..1 (64 cols each)
    const int ln = tid & 15;
    const int quad = (tid & 63) >> 4;

    half8 afr[4];
#pragma unroll
    for (int ks = 0; ks < 4; ++ks)
        afr[ks] = *(const half8*)(Of + (mt * 16 + ln) * PSTR + ks * 32 + quad * 8);

    f32x4 acc[4] = {};
#pragma unroll
    for (int nt = 0; nt < 4; ++nt) {
        const int n = nhf * 64 + nt * 16 + ln;
#pragma unroll
        for (int ks = 0; ks < 4; ++ks) {
            const half8 bf = *(const half8*)(wpT + (size_t)n * 128 + ks * 32 + quad * 8);
            acc[nt] = __builtin_amdgcn_mfma_f32_16x16x32_f16(afr[ks], bf, acc[nt], 0, 0, 0);
        }
    }

    // Cs (alias over vS)
#pragma unroll
    for (int nt = 0; nt < 4; ++nt) {
        const int n = nhf * 64 + nt * 16 + ln;
        const float bv = bproj[n];
#pragma unroll
        for (int r = 0; r < 4; ++r)
            Cs[(mt * 16 + quad * 4 + r) * 132 + n] = acc[nt][r] + bv;
    }
    __syncthreads();

    // ---- coalesced final stores ----
#pragma unroll
    for (int it = 0; it < 4; ++it) {
        int idx = it * 512 + tid;
        int m = idx >> 5;
        int c = idx & 31;
        float4 v = *(const float4*)(Cs + m * 132 + c * 4);
        const size_t pix = (size_t)b * 4096 + (size_t)(ty0 + (m >> 3)) * Wdim + tx0 + (m & 7);
        *(float4*)(outp + pix * 128 + c * 4) = v;
    }
}

// ---------------------------------------------------------------------------
extern "C" void kernel_launch(void* const* d_in, const int* in_sizes, int n_in,
                              void* d_out, int out_size, void* d_ws, size_t ws_size,
                              hipStream_t stream) {
    const float* x      = (const float*)d_in[0];
    const float* w_qkv  = (const float*)d_in[1];
    const float* b_qkv  = (const float*)d_in[2];
    const float* rpb    = (const float*)d_in[3];
    const float* w_proj = (const float*)d_in[4];
    const float* b_proj = (const float*)d_in[5];
    float* out = (float*)d_out;

    char* ws = (char*)d_ws;
    _Float16* qkvh = (_Float16*)ws;                   // 12,582,912 B
    _Float16* wqT  = (_Float16*)(ws + 12582912);      //     98,304 B
    _Float16* wpT  = (_Float16*)(ws + 12582912 + 98304);  // 32,768 B

    prep_weights<<<16, dim3(256), 0, stream>>>(w_qkv, w_proj, wqT, wpT);
    gemm_qkv_mfma<<<dim3(16384 / 64, 3), dim3(256), 0, stream>>>(x, wqT, b_qkv, qkvh);
    attn_proj<<<dim3(4, Hdim / ATS, Wdim / ATS), dim3(512), 0, stream>>>(
        qkvh, rpb, wpT, b_proj, out);
}

// Round 9
// 234.549 us; speedup vs baseline: 1.2170x; 1.2170x over previous
//
#include <hip/hip_runtime.h>
#include <cstddef>
#include <cstdint>

#define Hdim 64
#define Wdim 64
#define NH 4
#define DH 32
#define KW 7
#define QSCALE 0.17677669529663687f

typedef _Float16 v2h __attribute__((ext_vector_type(2)));
typedef _Float16 half8 __attribute__((ext_vector_type(8)));
typedef float f32x4 __attribute__((ext_vector_type(4)));

#if defined(__has_builtin)
#if __has_builtin(__builtin_amdgcn_fdot2)
#define HAVE_FDOT2 1
#endif
#endif

__device__ __forceinline__ float fdot2acc(v2h a, v2h b, float c) {
#ifdef HAVE_FDOT2
    return __builtin_amdgcn_fdot2(a, b, c, false);
#else
    return fmaf((float)a.x, (float)b.x, fmaf((float)a.y, (float)b.y, c));
#endif
}

union F16x8 {
    uint4 u;
    v2h h[4];
};

// ---------------------------------------------------------------------------
// Prep: transpose + fp16-convert weights. WT[n][k], k contiguous (128).
// ---------------------------------------------------------------------------
__global__ __launch_bounds__(256) void prep_weights(
    const float* __restrict__ wq, const float* __restrict__ wp,
    _Float16* __restrict__ wqT, _Float16* __restrict__ wpT)
{
    __shared__ float Ts[64][65];
    int blk = blockIdx.x;
    const float* src;
    _Float16* dst;
    int N, kt, nt;
    if (blk < 12) { src = wq; dst = wqT; N = 384; kt = blk / 6; nt = blk % 6; }
    else { blk -= 12; src = wp; dst = wpT; N = 128; kt = blk >> 1; nt = blk & 1; }
    const int k0 = kt * 64, n0 = nt * 64;
    const int tid = threadIdx.x;

#pragma unroll
    for (int it = 0; it < 16; ++it) {
        int idx = it * 256 + tid;
        int r = idx >> 6, c = idx & 63;
        Ts[r][c] = src[(size_t)(k0 + r) * N + n0 + c];
    }
    __syncthreads();
#pragma unroll
    for (int it = 0; it < 2; ++it) {
        int idx = it * 256 + tid;
        int n = idx >> 3;
        int kq = (idx & 7) * 8;
        _Float16 tmp[8];
#pragma unroll
        for (int j = 0; j < 8; ++j) tmp[j] = (_Float16)Ts[kq + j][n];
        *(uint4*)(dst + (size_t)(n0 + n) * 128 + k0 + kq) = *(const uint4*)tmp;
    }
}

// ---------------------------------------------------------------------------
// GEMM1 (MFMA): qkv = x @ w_qkv + b_qkv -> fp16 [sel][b*4+h][yx][32], q scaled.
// (R4 verbatim — LDS-swizzled coalesced epilogue, proven 119.7-us config.)
// ---------------------------------------------------------------------------
__global__ __launch_bounds__(256) void gemm_qkv_mfma(
    const float* __restrict__ A,      // x [16384][128]
    const _Float16* __restrict__ WT,  // [384][128]
    const float* __restrict__ bias,   // [384]
    _Float16* __restrict__ qkvh)      // [3][16][4096][32]
{
    __shared__ _Float16 As[64 * 136];
    const int m0 = blockIdx.x * 64;
    const int sel = blockIdx.y;
    const int n0 = sel * 128;
    const int tid = threadIdx.x;
    const int wv = tid >> 6;
    const int ln = tid & 15;
    const int quad = (tid & 63) >> 4;

#pragma unroll
    for (int it = 0; it < 8; ++it) {
        int idx = it * 256 + tid;
        int m = idx >> 5;
        int kq = (idx & 31) * 4;
        float4 a = *(const float4*)(A + (size_t)(m0 + m) * 128 + kq);
        _Float16 t[4] = {(_Float16)a.x, (_Float16)a.y, (_Float16)a.z, (_Float16)a.w};
        *(uint2*)(As + m * 136 + kq) = *(const uint2*)t;
    }
    __syncthreads();

    f32x4 acc[8] = {};
    const int mrow = wv * 16 + ln;
#pragma unroll
    for (int ks = 0; ks < 4; ++ks) {
        const half8 af = *(const half8*)(As + mrow * 136 + ks * 32 + quad * 8);
#pragma unroll
        for (int nt = 0; nt < 8; ++nt) {
            const half8 bf = *(const half8*)(WT + (size_t)(n0 + nt * 16 + ln) * 128 + ks * 32 + quad * 8);
            acc[nt] = __builtin_amdgcn_mfma_f32_16x16x32_f16(af, bf, acc[nt], 0, 0, 0);
        }
    }
    __syncthreads();

    const float qscale = (sel == 0) ? QSCALE : 1.0f;
#pragma unroll
    for (int nt = 0; nt < 8; ++nt) {
        const int n = nt * 16 + ln;
        const float bv = bias[n0 + n];
#pragma unroll
        for (int r = 0; r < 4; ++r) {
            const int m = wv * 16 + quad * 4 + r;
            As[m * 136 + n] = (_Float16)((acc[nt][r] + bv) * qscale);
        }
    }
    __syncthreads();

    const int b = m0 >> 12;
    const int yx0 = m0 & 4095;
#pragma unroll
    for (int h = 0; h < 4; ++h) {
        const int r = tid >> 2;
        const int c = tid & 3;
        uint4 v = *(const uint4*)(As + r * 136 + h * 32 + c * 8);
        *(uint4*)(qkvh + (((size_t)sel * 16 + b * 4 + h) * 4096 + yx0 + r) * 32 + c * 8) = v;
    }
}

// ---------------------------------------------------------------------------
// Fused local attention (quad-split, 256 thr). Conflict-free K/V LDS layout:
// [chunk][pos] planes — hot-path pos-stride is 16 B (8 consecutive pixels
// span all 32 banks), chunk-plane stride 3136 B = 64 mod 128 (2-way = free).
// R1-R8's [pos][chunk] stride-80B layout measured 2.8M conflict-cycles.
// Output fp16 (R3-proven numerics).
// ---------------------------------------------------------------------------
#define ATS 8
#define AMAXPOS 196
#define CPLANE (AMAXPOS * 8)   // halves per chunk-plane (196 pos x 8 halves)

__global__ __launch_bounds__(256, 4) void local_attn(
    const _Float16* __restrict__ qkvh,  // [3][16][4096][32]
    const float* __restrict__ rpb,      // [4][13][13]
    _Float16* __restrict__ outh)        // [16384][128]
{
    __shared__ _Float16 kS[4 * CPLANE];
    __shared__ _Float16 vS[4 * CPLANE];
    __shared__ float rS[169];

    const int bh = blockIdx.x;
    const int h = bh & 3;
    const int ty0 = blockIdx.y * ATS;
    const int tx0 = blockIdx.z * ATS;
    const int tid = threadIdx.x;

    const int lo_h = max(0, min(ty0 - 3, Hdim - KW));
    const int hi_h = min(ty0 + ATS - 4, Hdim - KW) + KW - 1;
    const int lo_w = max(0, min(tx0 - 3, Wdim - KW));
    const int hi_w = min(tx0 + ATS - 4, Wdim - KW) + KW - 1;
    const int ch = hi_h - lo_h + 1;
    const int cw = hi_w - lo_w + 1;
    const int npos = ch * cw;

    const _Float16* kbase = qkvh + (size_t)(16 + bh) * 131072;
    const _Float16* vbase = qkvh + (size_t)(32 + bh) * 131072;

    for (int idx = tid; idx < npos * 4; idx += 256) {
        const int pos = idx >> 2;
        const int c = idx & 3;
        const int ry = pos / cw;
        const int rx = pos - ry * cw;
        const size_t g = ((size_t)(lo_h + ry) * Wdim + (lo_w + rx)) * 32 + c * 8;
        *(uint4*)(kS + c * CPLANE + pos * 8) = *(const uint4*)(kbase + g);
    }
    for (int idx = tid; idx < npos * 4; idx += 256) {
        const int pos = idx >> 2;
        const int c = idx & 3;
        const int ry = pos / cw;
        const int rx = pos - ry * cw;
        const size_t g = ((size_t)(lo_h + ry) * Wdim + (lo_w + rx)) * 32 + c * 8;
        *(uint4*)(vS + c * CPLANE + pos * 8) = *(const uint4*)(vbase + g);
    }
    for (int i = tid; i < 169; i += 256) rS[i] = rpb[h * 169 + i];
    __syncthreads();

    const int p = tid >> 2;          // pixel 0..63
    const int q = tid & 3;           // dim quarter (chunk)
    const int py = p >> 3, px = p & 7;
    const int y = ty0 + py, x = tx0 + px;
    const int sh = max(0, min(y - 3, Hdim - KW));
    const int sw = max(0, min(x - 3, Wdim - KW));
    const int rb = sh - lo_h;
    const int cb = sw - lo_w;
    const int bh0 = sh - y + 6;
    const int bw0 = sw - x + 6;

    F16x8 qf;
    qf.u = *(const uint4*)(qkvh + (size_t)bh * 131072 + ((size_t)y * Wdim + x) * 32 + q * 8);

    const _Float16* kQ = kS + q * CPLANE;
    const _Float16* vQ = vS + q * CPLANE;

    float sc[49];
#pragma unroll
    for (int i = 0; i < KW; ++i) {
        const _Float16* kp = kQ + ((rb + i) * cw + cb) * 8;
        const int bi = (bh0 + i) * 13 + bw0;
#pragma unroll
        for (int j = 0; j < KW; ++j) {
            F16x8 kf;
            kf.u = *(const uint4*)(kp + j * 8);
            float s = fdot2acc(qf.h[0], kf.h[0],
                      fdot2acc(qf.h[1], kf.h[1],
                      fdot2acc(qf.h[2], kf.h[2],
                      fdot2acc(qf.h[3], kf.h[3], 0.0f))));
            s += __shfl_xor(s, 1);
            s += __shfl_xor(s, 2);
            sc[i * KW + j] = s + rS[bi + j];
        }
    }

    float mx = sc[0];
#pragma unroll
    for (int t = 1; t < 49; ++t) mx = fmaxf(mx, sc[t]);
    float l = 0.f;
#pragma unroll
    for (int t = 0; t < 49; ++t) { sc[t] = __expf(sc[t] - mx); l += sc[t]; }
    const float inv = 1.f / l;

    float o[8] = {};
#pragma unroll
    for (int i = 0; i < KW; ++i) {
        const _Float16* vp = vQ + ((rb + i) * cw + cb) * 8;
#pragma unroll
        for (int j = 0; j < KW; ++j) {
            F16x8 vf;
            vf.u = *(const uint4*)(vp + j * 8);
            const float w = sc[i * KW + j] * inv;
#pragma unroll
            for (int d = 0; d < 4; ++d) {
                o[2 * d + 0] = fmaf(w, (float)vf.h[d].x, o[2 * d + 0]);
                o[2 * d + 1] = fmaf(w, (float)vf.h[d].y, o[2 * d + 1]);
            }
        }
    }

    const size_t pix = (size_t)(bh >> 2) * 4096 + (size_t)y * Wdim + x;
    _Float16 oh[8];
#pragma unroll
    for (int d = 0; d < 8; ++d) oh[d] = (_Float16)o[d];
    *(uint4*)(outh + pix * 128 + h * DH + q * 8) = *(const uint4*)oh;
}

// ---------------------------------------------------------------------------
// GEMM2 (MFMA): out = attn(fp16) @ w_proj + b_proj, fp32 out. A staging is a
// pure uint4 copy. Epilogue via LDS -> full-row float4 coalesced stores.
// ---------------------------------------------------------------------------
__global__ __launch_bounds__(256) void gemm_proj_mfma(
    const _Float16* __restrict__ Ah,   // attn fp16 [16384][128]
    const _Float16* __restrict__ WT,   // [128][128]
    const float* __restrict__ bias,    // [128]
    float* __restrict__ C)             // [16384][128]
{
    __shared__ float Cs[64 * 132];               // 33.8 KB, aliased for As
    _Float16* As = (_Float16*)Cs;                // [64][136] halves

    const int m0 = blockIdx.x * 64;
    const int tid = threadIdx.x;
    const int wv = tid >> 6;
    const int ln = tid & 15;
    const int quad = (tid & 63) >> 4;

#pragma unroll
    for (int it = 0; it < 4; ++it) {
        int idx = it * 256 + tid;
        int m = idx >> 4;
        int kq = (idx & 15) * 8;
        *(uint4*)(As + m * 136 + kq) = *(const uint4*)(Ah + (size_t)(m0 + m) * 128 + kq);
    }
    __syncthreads();

    f32x4 acc[8] = {};
    const int mrow = wv * 16 + ln;
#pragma unroll
    for (int ks = 0; ks < 4; ++ks) {
        const half8 af = *(const half8*)(As + mrow * 136 + ks * 32 + quad * 8);
#pragma unroll
        for (int nt = 0; nt < 8; ++nt) {
            const half8 bf = *(const half8*)(WT + (size_t)(nt * 16 + ln) * 128 + ks * 32 + quad * 8);
            acc[nt] = __builtin_amdgcn_mfma_f32_16x16x32_f16(af, bf, acc[nt], 0, 0, 0);
        }
    }
    __syncthreads();   // done reading As; reuse memory for Cs

#pragma unroll
    for (int nt = 0; nt < 8; ++nt) {
        const int n = nt * 16 + ln;
        const float bv = bias[n];
#pragma unroll
        for (int r = 0; r < 4; ++r) {
            const int m = wv * 16 + quad * 4 + r;
            Cs[m * 132 + n] = acc[nt][r] + bv;
        }
    }
    __syncthreads();

#pragma unroll
    for (int it = 0; it < 8; ++it) {
        int idx = it * 256 + tid;
        int m = idx >> 5;
        int c = idx & 31;
        float4 v = *(const float4*)(Cs + m * 132 + c * 4);
        *(float4*)(C + (size_t)(m0 + m) * 128 + c * 4) = v;
    }
}

// ---------------------------------------------------------------------------
extern "C" void kernel_launch(void* const* d_in, const int* in_sizes, int n_in,
                              void* d_out, int out_size, void* d_ws, size_t ws_size,
                              hipStream_t stream) {
    const float* x      = (const float*)d_in[0];
    const float* w_qkv  = (const float*)d_in[1];
    const float* b_qkv  = (const float*)d_in[2];
    const float* rpb    = (const float*)d_in[3];
    const float* w_proj = (const float*)d_in[4];
    const float* b_proj = (const float*)d_in[5];
    float* out = (float*)d_out;

    char* ws = (char*)d_ws;
    _Float16* qkvh  = (_Float16*)ws;                    // 12,582,912 B
    _Float16* attnh = (_Float16*)(ws + 12582912);       //  4,194,304 B
    _Float16* wqT   = (_Float16*)(ws + 16777216);       //     98,304 B
    _Float16* wpT   = (_Float16*)(ws + 16875520);       //     32,768 B

    dim3 blk(256);
    prep_weights<<<16, blk, 0, stream>>>(w_qkv, w_proj, wqT, wpT);
    gemm_qkv_mfma<<<dim3(16384 / 64, 3), blk, 0, stream>>>(x, wqT, b_qkv, qkvh);
    local_attn<<<dim3(16, Hdim / ATS, Wdim / ATS), blk, 0, stream>>>(qkvh, rpb, attnh);
    gemm_proj_mfma<<<dim3(16384 / 64, 1), blk, 0, stream>>>(attnh, wpT, b_proj, out);
}